// Round 6
// baseline (82.919 us; speedup 1.0000x reference)
//
#include <hip/hip_runtime.h>

#define B_N 4096
#define POOL_N 45
#define PACK_N 15
#define E_N 512
#define D_N 8
#define V_N 30000

// ws layout (floats):
//   wt   [512][24]   : transposed weights, col j: 0..7=q_w, 8..15=k_w, 16..23=v_w
//   tab  [V][24]     : per-card projections, 0..7=q, 8..15=k(relu), 16..23=v(relu)
//   aux  [B][32]     : 0..7 k_win, 8..15 v_win, 16..23 k_rank, 24..31 v_rank
//   part [2][V][24]  : per-e-half partial sums for tab
#define WT_SZ  (E_N * 24)
#define TAB_SZ (V_N * 24)
#define AUX_SZ (B_N * 32)

// ---------------------------------------------------------------- K0: W^T ---
__global__ __launch_bounds__(256) void k_transpose_w(const float* __restrict__ q_w,
                                                     const float* __restrict__ k_w,
                                                     const float* __restrict__ v_w,
                                                     float* __restrict__ wt) {
  int i = blockIdx.x * 256 + threadIdx.x;  // [0, 512*24)
  if (i >= E_N * 24) return;
  int e = i / 24, j = i % 24;
  float val = (j < 8) ? q_w[j * E_N + e]
            : (j < 16) ? k_w[(j - 8) * E_N + e]
                       : v_w[(j - 16) * E_N + e];
  wt[i] = val;
}

// --------------------------------------------------- K1: projection table ---
// grid (469, 2): blockIdx.y = e-half. 8 waves/block, 64 rows/block; wave w
// covers e-slice [half*256 + w*32, +32) (weight addr wave-uniform -> s_load
// broadcast); lane = row. LDS reduce over the 8 slices -> part[half].
// 938 blocks ~= 3.7/CU; LDS 51.2KB caps 3 blocks/CU -> ~24 waves/CU.
__global__ __launch_bounds__(512) void k_build_tab(const float* __restrict__ emb,
                                                   const float* __restrict__ wt,
                                                   float* __restrict__ part) {
  __shared__ float red[8][64][25];  // stride 25: conflict-free
  int lane = threadIdx.x & 63;
  int w = __builtin_amdgcn_readfirstlane(threadIdx.x >> 6);  // 0..7, uniform
  int half = blockIdx.y;
  int r = blockIdx.x * 64 + lane;
  float acc[24];
#pragma unroll
  for (int j = 0; j < 24; ++j) acc[j] = 0.f;
  if (r < V_N) {
    const float* a = emb + (size_t)r * E_N + half * 256 + w * 32;
    const float* wp = wt + (half * 256 + w * 32) * 24;
#pragma unroll
    for (int i = 0; i < 8; ++i) {  // 8 x float4 = 32 e-values, fully unrolled
      float4 av = ((const float4*)a)[i];
      float xs[4] = {av.x, av.y, av.z, av.w};
#pragma unroll
      for (int c = 0; c < 4; ++c) {
        float x = xs[c];
        float xr = fmaxf(x, 0.f);
        const float* wr = wp + (i * 4 + c) * 24;
#pragma unroll
        for (int j = 0; j < 8; ++j) acc[j] = fmaf(x, wr[j], acc[j]);
#pragma unroll
        for (int j = 8; j < 24; ++j) acc[j] = fmaf(xr, wr[j], acc[j]);
      }
    }
  }
#pragma unroll
  for (int j = 0; j < 24; ++j) red[w][lane][j] = acc[j];
  __syncthreads();
  float* po = part + (size_t)half * TAB_SZ;
  for (int o = threadIdx.x; o < 1536; o += 512) {  // 64 rows x 24 cols
    int row = o / 24, col = o - row * 24;
    int r_out = blockIdx.x * 64 + row;
    if (r_out < V_N) {
      float v = 0.f;
#pragma unroll
      for (int s = 0; s < 8; ++s) v += red[s][row][col];
      po[(size_t)r_out * 24 + col] = v;
    }
  }
}

// ------------------------------------------------ K1b: sum the two halves ---
__global__ __launch_bounds__(256) void k_reduce_tab(const float* __restrict__ part,
                                                    float* __restrict__ tab) {
  int i = blockIdx.x * 256 + threadIdx.x;  // float4 index, TAB_SZ/4 = 180000
  if (i < TAB_SZ / 4) {
    float4 a = ((const float4*)part)[i];
    float4 b = ((const float4*)(part + TAB_SZ))[i];
    float4 o = {a.x + b.x, a.y + b.y, a.z + b.z, a.w + b.w};
    ((float4*)tab)[i] = o;
  }
}

// ------------------------------------------- K2: win/rank k,v rows per b ---
// grid (B/16, 2): 512 blocks. Block 256: thread = (seg 0..15, b-local 0..15);
// each thread covers 32 e-values; LDS reduce over 16 segs.
__global__ __launch_bounds__(256) void k_build_aux(const float* __restrict__ wins,
                                                   const float* __restrict__ ranks,
                                                   const float* __restrict__ win_w,
                                                   const float* __restrict__ win_b,
                                                   const float* __restrict__ rank_w,
                                                   const float* __restrict__ rank_b,
                                                   const float* __restrict__ wt,
                                                   float* __restrict__ aux) {
  __shared__ float red[16][16][17];
  int t = threadIdx.x;
  int bl = t & 15, seg = t >> 4;
  int which = blockIdx.y;
  int b = blockIdx.x * 16 + bl;
  float s = which ? ranks[b] : wins[b];
  const float* ww = which ? rank_w : win_w;
  const float* wb = which ? rank_b : win_b;
  float acc[16];
#pragma unroll
  for (int j = 0; j < 16; ++j) acc[j] = 0.f;
  int e0 = seg * 32;
#pragma unroll 4
  for (int e = e0; e < e0 + 32; ++e) {
    float x = fmaf(s, ww[e], wb[e]);
    float xr = fmaxf(x, 0.f);
    const float* wr = wt + e * 24 + 8;  // k(8) + v(8) columns
#pragma unroll
    for (int j = 0; j < 16; ++j) acc[j] = fmaf(xr, wr[j], acc[j]);
  }
#pragma unroll
  for (int j = 0; j < 16; ++j) red[seg][bl][j] = acc[j];
  __syncthreads();
  int bi = t >> 4, j = t & 15;
  float v = 0.f;
#pragma unroll
  for (int sg = 0; sg < 16; ++sg) v += red[sg][bi][j];
  aux[(size_t)(blockIdx.x * 16 + bi) * 32 + which * 16 + j] = v;
}

// ----------------------------------------------------- K3: attention + out --
// (exact R3 version — known pass) 32-lane group per b; lane = pack slot k.
// Single pass, online softmax; pool indices prefetched + uniform shfl bcast.
__global__ __launch_bounds__(256) void k_main(const int* __restrict__ pool,
                                              const int* __restrict__ pack,
                                              const float* __restrict__ tab,
                                              const float* __restrict__ aux,
                                              const float* __restrict__ sc_w,
                                              const float* __restrict__ sc_b,
                                              float* __restrict__ out) {
  int grp = threadIdx.x >> 5;
  int lane = threadIdx.x & 31;
  int b = blockIdx.x * 8 + grp;
  // prefetch pool indices: lane l holds p=l and p=32+l
  int i0 = pool[(size_t)b * POOL_N + lane];
  int i1 = (lane < POOL_N - 32) ? pool[(size_t)b * POOL_N + 32 + lane] : 0;
  int k = (lane < PACK_N) ? lane : 0;  // clamp idles to avoid OOB gathers
  int qidx = pack[(size_t)b * PACK_N + k];
  const float* qr = tab + (size_t)qidx * 24;
  float4 qa = *(const float4*)qr;
  float4 qb = *(const float4*)(qr + 4);
  const float rs = 0.35355339059327373f;  // 1/sqrt(8)
  const float* auxb = aux + (size_t)b * 32;

  float m = 0.f, sum = 0.f;  // scores relu'd -> max >= 0
  float ctx[8] = {0.f, 0.f, 0.f, 0.f, 0.f, 0.f, 0.f, 0.f};

  auto att_step = [&](const float* kr) {
    float4 k0 = *(const float4*)kr;
    float4 k1 = *(const float4*)(kr + 4);
    float4 v0 = *(const float4*)(kr + 8);
    float4 v1 = *(const float4*)(kr + 12);
    float d = qa.x * k0.x;
    d = fmaf(qa.y, k0.y, d);
    d = fmaf(qa.z, k0.z, d);
    d = fmaf(qa.w, k0.w, d);
    d = fmaf(qb.x, k1.x, d);
    d = fmaf(qb.y, k1.y, d);
    d = fmaf(qb.z, k1.z, d);
    d = fmaf(qb.w, k1.w, d);
    d = fmaxf(d * rs, 0.f);
    // one transcendental per step: t = exp(-|d-m|) serves as either the
    // rescale (d>m) or the new term (d<=m); the other factor is exactly 1.
    float t = __expf(-fabsf(d - m));
    bool up = d > m;
    float sc = up ? t : 1.f;
    float e = up ? 1.f : t;
    m = fmaxf(m, d);
    sum = fmaf(sum, sc, e);
    ctx[0] = fmaf(ctx[0], sc, e * v0.x);
    ctx[1] = fmaf(ctx[1], sc, e * v0.y);
    ctx[2] = fmaf(ctx[2], sc, e * v0.z);
    ctx[3] = fmaf(ctx[3], sc, e * v0.w);
    ctx[4] = fmaf(ctx[4], sc, e * v1.x);
    ctx[5] = fmaf(ctx[5], sc, e * v1.y);
    ctx[6] = fmaf(ctx[6], sc, e * v1.z);
    ctx[7] = fmaf(ctx[7], sc, e * v1.w);
  };

#pragma unroll 8
  for (int p = 0; p < 32; ++p) {
    int pi = __shfl(i0, p, 32);
    att_step(tab + (size_t)pi * 24 + 8);
  }
#pragma unroll
  for (int p = 0; p < 13; ++p) {
    int pi = __shfl(i1, p, 32);
    att_step(tab + (size_t)pi * 24 + 8);
  }
  att_step(auxb);        // win  (k at +0, v at +8)
  att_step(auxb + 16);   // rank

  float inv = 1.f / sum;
  float logit = 0.f;
#pragma unroll
  for (int d0 = 0; d0 < 8; ++d0) {
    float c = ctx[d0] * inv;
    c = (c > 0.f) ? c : 0.01f * c;  // leaky_relu
    logit = fmaf(c, sc_w[d0], logit);
  }
  logit += sc_b[0];
  if (lane < PACK_N) out[(size_t)b * PACK_N + lane] = logit;
}

extern "C" void kernel_launch(void* const* d_in, const int* in_sizes, int n_in,
                              void* d_out, int out_size, void* d_ws, size_t ws_size,
                              hipStream_t stream) {
  const int* pool = (const int*)d_in[0];
  const int* pack = (const int*)d_in[1];
  const float* wins = (const float*)d_in[2];
  const float* ranks = (const float*)d_in[3];
  const float* emb = (const float*)d_in[4];
  const float* win_w = (const float*)d_in[5];
  const float* win_b = (const float*)d_in[6];
  const float* rank_w = (const float*)d_in[7];
  const float* rank_b = (const float*)d_in[8];
  const float* q_w = (const float*)d_in[9];
  const float* k_w = (const float*)d_in[10];
  const float* v_w = (const float*)d_in[11];
  const float* sc_w = (const float*)d_in[12];
  const float* sc_b = (const float*)d_in[13];

  float* ws = (float*)d_ws;
  float* wt = ws;
  float* tab = ws + WT_SZ;
  float* aux = ws + WT_SZ + TAB_SZ;
  float* part = ws + WT_SZ + TAB_SZ + AUX_SZ;
  float* out = (float*)d_out;

  hipLaunchKernelGGL(k_transpose_w, dim3(48), dim3(256), 0, stream,
                     q_w, k_w, v_w, wt);
  hipLaunchKernelGGL(k_build_tab, dim3((V_N + 63) / 64, 2), dim3(512), 0, stream,
                     emb, wt, part);
  hipLaunchKernelGGL(k_reduce_tab, dim3((TAB_SZ / 4 + 255) / 256), dim3(256), 0, stream,
                     part, tab);
  hipLaunchKernelGGL(k_build_aux, dim3(B_N / 16, 2), dim3(256), 0, stream,
                     wins, ranks, win_w, win_b, rank_w, rank_b, wt, aux);
  hipLaunchKernelGGL(k_main, dim3(B_N / 8), dim3(256), 0, stream,
                     pool, pack, tab, aux, sc_w, sc_b, out);
}

// Round 7
// 63.402 us; speedup vs baseline: 1.3078x; 1.3078x over previous
//
#include <hip/hip_runtime.h>

#define B_N 4096
#define POOL_N 45
#define PACK_N 15
#define E_N 512
#define D_N 8
#define V_N 30000

// Padded stride 32 everywhere (128B rows -> single-line gathers in k_main).
// ws layout (floats):
//   wt   [512][32]   : transposed weights, col j: 0..7=q, 8..15=k, 16..23=v, 24..31=0
//   tab  [V][32]     : per-card projections, 0..7=q, 8..15=k(relu), 16..23=v(relu)
//   aux  [B][32]     : 0..7 k_win, 8..15 v_win, 16..23 k_rank, 24..31 v_rank
//   part [2][V][32]  : per-e-half partial sums for tab
#define WT_SZ  (E_N * 32)
#define TAB_SZ (V_N * 32)
#define AUX_SZ (B_N * 32)

// ---------------------------------------------------------------- K0: W^T ---
__global__ __launch_bounds__(256) void k_transpose_w(const float* __restrict__ q_w,
                                                     const float* __restrict__ k_w,
                                                     const float* __restrict__ v_w,
                                                     float* __restrict__ wt) {
  int i = blockIdx.x * 256 + threadIdx.x;  // [0, 512*32)
  if (i >= E_N * 32) return;
  int e = i >> 5, j = i & 31;
  float val = (j < 8) ? q_w[j * E_N + e]
            : (j < 16) ? k_w[(j - 8) * E_N + e]
            : (j < 24) ? v_w[(j - 16) * E_N + e]
                       : 0.f;
  wt[i] = val;
}

// --------------------------------------------------- K1: projection table ---
// Tiled GEMM. grid (469, 2): y = e-half (256 e each). Block 256 = 4 waves.
// Per iter (4 iters x 64 e): stage emb tile [64 rows][64 e] into LDS with
// COALESCED loads (per wave-instr: 4 rows x 256B contiguous = 8 cache lines,
// vs 64 lines/instr in the old lane=row layout -> MSHR-friendly), stage wt
// tile [64 e][32 cols]; then lane = (row, colgroup-of-8) accumulates from
// LDS. acc[8] per lane; no cross-lane reduce (cols split, e accumulated).
__global__ __launch_bounds__(256) void k_build_tab(const float* __restrict__ emb,
                                                   const float* __restrict__ wt,
                                                   float* __restrict__ part) {
  __shared__ float et[64 * 68];   // emb tile, row stride 68 (16B-aligned, low-conflict)
  __shared__ float wtt[64 * 32];  // weight tile
  int t = threadIdx.x;
  int lane = t & 63;
  int w = t >> 6;                  // wave 0..3
  int half = blockIdx.y;
  int row0 = blockIdx.x * 64;
  int rloc = w * 16 + (lane >> 2); // 0..63: this lane's row
  int cg = lane & 3;               // colgroup: 8 cols each
  int srow = t >> 4;               // staging: 0..15 (+16 per sub)
  int se = (t & 15) * 4;
  float acc[8];
#pragma unroll
  for (int j = 0; j < 8; ++j) acc[j] = 0.f;

  for (int it = 0; it < 4; ++it) {
    int eb = half * 256 + it * 64;
    __syncthreads();  // previous compute done before overwriting tiles
    // stage emb tile: 4096 floats, 4 x float4 per thread, coalesced
#pragma unroll
    for (int sub = 0; sub < 4; ++sub) {
      int sr = srow + sub * 16;
      int gr = row0 + sr;
      gr = (gr < V_N) ? gr : V_N - 1;  // clamp (stores guarded later)
      float4 v = *(const float4*)(emb + (size_t)gr * E_N + eb + se);
      *(float4*)(et + sr * 68 + se) = v;
    }
    // stage wt tile: 2048 floats, linear copy
#pragma unroll
    for (int sub = 0; sub < 2; ++sub) {
      int F = t * 4 + sub * 1024;
      *(float4*)(wtt + F) = *(const float4*)(wt + eb * 32 + F);
    }
    __syncthreads();
    // accumulate from LDS
    const float* er = et + rloc * 68;
#pragma unroll
    for (int e4 = 0; e4 < 16; ++e4) {
      float4 av = *(const float4*)(er + e4 * 4);
      float xs[4] = {av.x, av.y, av.z, av.w};
#pragma unroll
      for (int j = 0; j < 4; ++j) {
        float x = xs[j];
        float xu = cg ? fmaxf(x, 0.f) : x;  // cg0 = q (raw), cg1/2 = k/v (relu)
        const float* wr = wtt + (e4 * 4 + j) * 32 + cg * 8;
        float4 w0 = *(const float4*)wr;
        float4 w1 = *(const float4*)(wr + 4);
        acc[0] = fmaf(xu, w0.x, acc[0]);
        acc[1] = fmaf(xu, w0.y, acc[1]);
        acc[2] = fmaf(xu, w0.z, acc[2]);
        acc[3] = fmaf(xu, w0.w, acc[3]);
        acc[4] = fmaf(xu, w1.x, acc[4]);
        acc[5] = fmaf(xu, w1.y, acc[5]);
        acc[6] = fmaf(xu, w1.z, acc[6]);
        acc[7] = fmaf(xu, w1.w, acc[7]);
      }
    }
  }
  int grow = row0 + rloc;
  if (grow < V_N) {
    float* po = part + (size_t)half * TAB_SZ + (size_t)grow * 32 + cg * 8;
    float4 o0 = {acc[0], acc[1], acc[2], acc[3]};
    float4 o1 = {acc[4], acc[5], acc[6], acc[7]};
    *(float4*)po = o0;
    *(float4*)(po + 4) = o1;
  }
}

// ------------------------------------------------ K1b: sum the two halves ---
__global__ __launch_bounds__(256) void k_reduce_tab(const float* __restrict__ part,
                                                    float* __restrict__ tab) {
  int i = blockIdx.x * 256 + threadIdx.x;  // float4 index, TAB_SZ/4 = 240000
  if (i < TAB_SZ / 4) {
    float4 a = ((const float4*)part)[i];
    float4 b = ((const float4*)(part + TAB_SZ))[i];
    float4 o = {a.x + b.x, a.y + b.y, a.z + b.z, a.w + b.w};
    ((float4*)tab)[i] = o;
  }
}

// ------------------------------------------- K2: win/rank k,v rows per b ---
// grid (B/16, 2): 512 blocks. Block 256: thread = (seg 0..15, b-local 0..15);
// each thread covers 32 e-values; LDS reduce over 16 segs.
__global__ __launch_bounds__(256) void k_build_aux(const float* __restrict__ wins,
                                                   const float* __restrict__ ranks,
                                                   const float* __restrict__ win_w,
                                                   const float* __restrict__ win_b,
                                                   const float* __restrict__ rank_w,
                                                   const float* __restrict__ rank_b,
                                                   const float* __restrict__ wt,
                                                   float* __restrict__ aux) {
  __shared__ float red[16][16][17];
  int t = threadIdx.x;
  int bl = t & 15, seg = t >> 4;
  int which = blockIdx.y;
  int b = blockIdx.x * 16 + bl;
  float s = which ? ranks[b] : wins[b];
  const float* ww = which ? rank_w : win_w;
  const float* wb = which ? rank_b : win_b;
  float acc[16];
#pragma unroll
  for (int j = 0; j < 16; ++j) acc[j] = 0.f;
  int e0 = seg * 32;
#pragma unroll 4
  for (int e = e0; e < e0 + 32; ++e) {
    float x = fmaf(s, ww[e], wb[e]);
    float xr = fmaxf(x, 0.f);
    const float* wr = wt + e * 32 + 8;  // k(8) + v(8) columns
#pragma unroll
    for (int j = 0; j < 16; ++j) acc[j] = fmaf(xr, wr[j], acc[j]);
  }
#pragma unroll
  for (int j = 0; j < 16; ++j) red[seg][bl][j] = acc[j];
  __syncthreads();
  int bi = t >> 4, j = t & 15;
  float v = 0.f;
#pragma unroll
  for (int sg = 0; sg < 16; ++sg) v += red[sg][bi][j];
  aux[(size_t)(blockIdx.x * 16 + bi) * 32 + which * 16 + j] = v;
}

// ----------------------------------------------------- K3: attention + out --
// (R3 structure — known pass; only tab stride 24 -> 32.) 32-lane group per b.
__global__ __launch_bounds__(256) void k_main(const int* __restrict__ pool,
                                              const int* __restrict__ pack,
                                              const float* __restrict__ tab,
                                              const float* __restrict__ aux,
                                              const float* __restrict__ sc_w,
                                              const float* __restrict__ sc_b,
                                              float* __restrict__ out) {
  int grp = threadIdx.x >> 5;
  int lane = threadIdx.x & 31;
  int b = blockIdx.x * 8 + grp;
  // prefetch pool indices: lane l holds p=l and p=32+l
  int i0 = pool[(size_t)b * POOL_N + lane];
  int i1 = (lane < POOL_N - 32) ? pool[(size_t)b * POOL_N + 32 + lane] : 0;
  int k = (lane < PACK_N) ? lane : 0;  // clamp idles to avoid OOB gathers
  int qidx = pack[(size_t)b * PACK_N + k];
  const float* qr = tab + (size_t)qidx * 32;
  float4 qa = *(const float4*)qr;
  float4 qb = *(const float4*)(qr + 4);
  const float rs = 0.35355339059327373f;  // 1/sqrt(8)
  const float* auxb = aux + (size_t)b * 32;

  float m = 0.f, sum = 0.f;  // scores relu'd -> max >= 0
  float ctx[8] = {0.f, 0.f, 0.f, 0.f, 0.f, 0.f, 0.f, 0.f};

  auto att_step = [&](const float* kr) {
    float4 k0 = *(const float4*)kr;
    float4 k1 = *(const float4*)(kr + 4);
    float4 v0 = *(const float4*)(kr + 8);
    float4 v1 = *(const float4*)(kr + 12);
    float d = qa.x * k0.x;
    d = fmaf(qa.y, k0.y, d);
    d = fmaf(qa.z, k0.z, d);
    d = fmaf(qa.w, k0.w, d);
    d = fmaf(qb.x, k1.x, d);
    d = fmaf(qb.y, k1.y, d);
    d = fmaf(qb.z, k1.z, d);
    d = fmaf(qb.w, k1.w, d);
    d = fmaxf(d * rs, 0.f);
    // one transcendental per step: t = exp(-|d-m|) serves as either the
    // rescale (d>m) or the new term (d<=m); the other factor is exactly 1.
    float t = __expf(-fabsf(d - m));
    bool up = d > m;
    float sc = up ? t : 1.f;
    float e = up ? 1.f : t;
    m = fmaxf(m, d);
    sum = fmaf(sum, sc, e);
    ctx[0] = fmaf(ctx[0], sc, e * v0.x);
    ctx[1] = fmaf(ctx[1], sc, e * v0.y);
    ctx[2] = fmaf(ctx[2], sc, e * v0.z);
    ctx[3] = fmaf(ctx[3], sc, e * v0.w);
    ctx[4] = fmaf(ctx[4], sc, e * v1.x);
    ctx[5] = fmaf(ctx[5], sc, e * v1.y);
    ctx[6] = fmaf(ctx[6], sc, e * v1.z);
    ctx[7] = fmaf(ctx[7], sc, e * v1.w);
  };

#pragma unroll 8
  for (int p = 0; p < 32; ++p) {
    int pi = __shfl(i0, p, 32);
    att_step(tab + (size_t)pi * 32 + 8);
  }
#pragma unroll
  for (int p = 0; p < 13; ++p) {
    int pi = __shfl(i1, p, 32);
    att_step(tab + (size_t)pi * 32 + 8);
  }
  att_step(auxb);        // win  (k at +0, v at +8)
  att_step(auxb + 16);   // rank

  float inv = 1.f / sum;
  float logit = 0.f;
#pragma unroll
  for (int d0 = 0; d0 < 8; ++d0) {
    float c = ctx[d0] * inv;
    c = (c > 0.f) ? c : 0.01f * c;  // leaky_relu
    logit = fmaf(c, sc_w[d0], logit);
  }
  logit += sc_b[0];
  if (lane < PACK_N) out[(size_t)b * PACK_N + lane] = logit;
}

extern "C" void kernel_launch(void* const* d_in, const int* in_sizes, int n_in,
                              void* d_out, int out_size, void* d_ws, size_t ws_size,
                              hipStream_t stream) {
  const int* pool = (const int*)d_in[0];
  const int* pack = (const int*)d_in[1];
  const float* wins = (const float*)d_in[2];
  const float* ranks = (const float*)d_in[3];
  const float* emb = (const float*)d_in[4];
  const float* win_w = (const float*)d_in[5];
  const float* win_b = (const float*)d_in[6];
  const float* rank_w = (const float*)d_in[7];
  const float* rank_b = (const float*)d_in[8];
  const float* q_w = (const float*)d_in[9];
  const float* k_w = (const float*)d_in[10];
  const float* v_w = (const float*)d_in[11];
  const float* sc_w = (const float*)d_in[12];
  const float* sc_b = (const float*)d_in[13];

  float* ws = (float*)d_ws;
  float* wt = ws;
  float* tab = ws + WT_SZ;
  float* aux = ws + WT_SZ + TAB_SZ;
  float* part = ws + WT_SZ + TAB_SZ + AUX_SZ;
  float* out = (float*)d_out;

  hipLaunchKernelGGL(k_transpose_w, dim3(WT_SZ / 256), dim3(256), 0, stream,
                     q_w, k_w, v_w, wt);
  hipLaunchKernelGGL(k_build_tab, dim3((V_N + 63) / 64, 2), dim3(256), 0, stream,
                     emb, wt, part);
  hipLaunchKernelGGL(k_reduce_tab, dim3(TAB_SZ / 4 / 256 + 1), dim3(256), 0, stream,
                     part, tab);
  hipLaunchKernelGGL(k_build_aux, dim3(B_N / 16, 2), dim3(256), 0, stream,
                     wins, ranks, win_w, win_b, rank_w, rank_b, wt, aux);
  hipLaunchKernelGGL(k_main, dim3(B_N / 8), dim3(256), 0, stream,
                     pool, pack, tab, aux, sc_w, sc_b, out);
}

// Round 8
// 61.227 us; speedup vs baseline: 1.3543x; 1.0355x over previous
//
#include <hip/hip_runtime.h>

#define B_N 4096
#define POOL_N 45
#define PACK_N 15
#define E_N 512
#define D_N 8
#define V_N 30000

// ws layout (floats):
//   wt  [512][24]  : transposed weights, col j: 0..7=q_w, 8..15=k_w, 16..23=v_w
//   tab [V][24]    : per-card projections, 0..7=q, 8..15=k(relu), 16..23=v(relu)
//   aux [B][32]    : 0..7 k_win, 8..15 v_win, 16..23 k_rank, 24..31 v_rank
#define WT_SZ  (E_N * 24)
#define TAB_SZ (V_N * 24)
#define AUX_SZ (B_N * 32)

// ---------------------------------------------------------------- K0: W^T ---
__global__ __launch_bounds__(256) void k_transpose_w(const float* __restrict__ q_w,
                                                     const float* __restrict__ k_w,
                                                     const float* __restrict__ v_w,
                                                     float* __restrict__ wt) {
  int i = blockIdx.x * 256 + threadIdx.x;  // [0, 512*24)
  if (i >= E_N * 24) return;
  int e = i / 24, j = i % 24;
  float val = (j < 8) ? q_w[j * E_N + e]
            : (j < 16) ? k_w[(j - 8) * E_N + e]
                       : v_w[(j - 16) * E_N + e];
  wt[i] = val;
}

// --------------------------------------------------- K1: projection table ---
// Hybrid of R3 (s_load weights, lane=row compute) and R7 (coalesced emb):
// 4 iters x 128 e: stage emb tile COALESCED (float4 per lane, 16 lines/instr)
// into e-major LDS [128 e][65] (odd stride -> conflict-free lane=row reads);
// compute: wave w covers 32 e, weights from GLOBAL wt at wave-uniform addr
// (s_load broadcast, zero LDS/VALU cost), x via ds_read_b32 (2-way = free).
// LDS partial reduce over the 4 waves (reusing the tile buffer) -> tab.
__global__ __launch_bounds__(256) void k_build_tab(const float* __restrict__ emb,
                                                   const float* __restrict__ wt,
                                                   float* __restrict__ tab) {
  __shared__ float lds[128 * 65];  // 33.3 KB; reused as red[4][64][25] (6400 w)
  int t = threadIdx.x;
  int lane = t & 63;
  int w = __builtin_amdgcn_readfirstlane(t >> 6);  // 0..3, uniform
  int row0 = blockIdx.x * 64;
  int f4 = t & 31;   // which float4 of the 128-e chunk
  int sr0 = t >> 5;  // 0..7
  float acc[24];
#pragma unroll
  for (int j = 0; j < 24; ++j) acc[j] = 0.f;

  for (int it = 0; it < 4; ++it) {
    int eb = it * 128;
    __syncthreads();  // previous compute done before overwriting tile
    // stage: 8 float4 per thread, coalesced global reads, e-major LDS stores
#pragma unroll
    for (int sub = 0; sub < 8; ++sub) {
      int sr = sub * 8 + sr0;            // 0..63
      int gr = row0 + sr;
      if (gr > V_N - 1) gr = V_N - 1;    // clamp (tab store guarded later)
      float4 v = *(const float4*)(emb + (size_t)gr * E_N + eb + f4 * 4);
      float* d = lds + (f4 * 4) * 65 + sr;
      d[0] = v.x; d[65] = v.y; d[130] = v.z; d[195] = v.w;
    }
    __syncthreads();
    // compute: wave w handles e-slice [eb + w*32, +32), lane = row
    const float* wp = wt + (size_t)(eb + w * 32) * 24;
    const float* ep = lds + (w * 32) * 65 + lane;
#pragma unroll
    for (int el = 0; el < 32; ++el) {
      float x = ep[el * 65];
      float xr = fmaxf(x, 0.f);
      const float* wr = wp + el * 24;
#pragma unroll
      for (int j = 0; j < 8; ++j) acc[j] = fmaf(x, wr[j], acc[j]);
#pragma unroll
      for (int j = 8; j < 24; ++j) acc[j] = fmaf(xr, wr[j], acc[j]);
    }
  }
  __syncthreads();  // all tile reads done; reuse lds as red
#pragma unroll
  for (int j = 0; j < 24; ++j) lds[w * 1600 + lane * 25 + j] = acc[j];
  __syncthreads();
  for (int o = t; o < 1536; o += 256) {  // 64 rows x 24 cols
    int row = o / 24, col = o - row * 24;
    int r_out = row0 + row;
    if (r_out < V_N) {
      float v = lds[row * 25 + col] + lds[1600 + row * 25 + col]
              + lds[3200 + row * 25 + col] + lds[4800 + row * 25 + col];
      tab[(size_t)r_out * 24 + col] = v;
    }
  }
}

// ------------------------------------------- K2: win/rank k,v rows per b ---
// grid (B/16, 2): 512 blocks. Block 256: thread = (seg 0..15, b-local 0..15);
// each thread covers 32 e-values; LDS reduce over 16 segs.
__global__ __launch_bounds__(256) void k_build_aux(const float* __restrict__ wins,
                                                   const float* __restrict__ ranks,
                                                   const float* __restrict__ win_w,
                                                   const float* __restrict__ win_b,
                                                   const float* __restrict__ rank_w,
                                                   const float* __restrict__ rank_b,
                                                   const float* __restrict__ wt,
                                                   float* __restrict__ aux) {
  __shared__ float red[16][16][17];
  int t = threadIdx.x;
  int bl = t & 15, seg = t >> 4;
  int which = blockIdx.y;
  int b = blockIdx.x * 16 + bl;
  float s = which ? ranks[b] : wins[b];
  const float* ww = which ? rank_w : win_w;
  const float* wb = which ? rank_b : win_b;
  float acc[16];
#pragma unroll
  for (int j = 0; j < 16; ++j) acc[j] = 0.f;
  int e0 = seg * 32;
#pragma unroll 4
  for (int e = e0; e < e0 + 32; ++e) {
    float x = fmaf(s, ww[e], wb[e]);
    float xr = fmaxf(x, 0.f);
    const float* wr = wt + e * 24 + 8;  // k(8) + v(8) columns
#pragma unroll
    for (int j = 0; j < 16; ++j) acc[j] = fmaf(xr, wr[j], acc[j]);
  }
#pragma unroll
  for (int j = 0; j < 16; ++j) red[seg][bl][j] = acc[j];
  __syncthreads();
  int bi = t >> 4, j = t & 15;
  float v = 0.f;
#pragma unroll
  for (int sg = 0; sg < 16; ++sg) v += red[sg][bi][j];
  aux[(size_t)(blockIdx.x * 16 + bi) * 32 + which * 16 + j] = v;
}

// ----------------------------------------------------- K3: attention + out --
// (exact R3 version — known pass) 32-lane group per b; lane = pack slot k.
// Single pass, online softmax; pool indices prefetched + uniform shfl bcast.
__global__ __launch_bounds__(256) void k_main(const int* __restrict__ pool,
                                              const int* __restrict__ pack,
                                              const float* __restrict__ tab,
                                              const float* __restrict__ aux,
                                              const float* __restrict__ sc_w,
                                              const float* __restrict__ sc_b,
                                              float* __restrict__ out) {
  int grp = threadIdx.x >> 5;
  int lane = threadIdx.x & 31;
  int b = blockIdx.x * 8 + grp;
  // prefetch pool indices: lane l holds p=l and p=32+l
  int i0 = pool[(size_t)b * POOL_N + lane];
  int i1 = (lane < POOL_N - 32) ? pool[(size_t)b * POOL_N + 32 + lane] : 0;
  int k = (lane < PACK_N) ? lane : 0;  // clamp idles to avoid OOB gathers
  int qidx = pack[(size_t)b * PACK_N + k];
  const float* qr = tab + (size_t)qidx * 24;
  float4 qa = *(const float4*)qr;
  float4 qb = *(const float4*)(qr + 4);
  const float rs = 0.35355339059327373f;  // 1/sqrt(8)
  const float* auxb = aux + (size_t)b * 32;

  float m = 0.f, sum = 0.f;  // scores relu'd -> max >= 0
  float ctx[8] = {0.f, 0.f, 0.f, 0.f, 0.f, 0.f, 0.f, 0.f};

  auto att_step = [&](const float* kr) {
    float4 k0 = *(const float4*)kr;
    float4 k1 = *(const float4*)(kr + 4);
    float4 v0 = *(const float4*)(kr + 8);
    float4 v1 = *(const float4*)(kr + 12);
    float d = qa.x * k0.x;
    d = fmaf(qa.y, k0.y, d);
    d = fmaf(qa.z, k0.z, d);
    d = fmaf(qa.w, k0.w, d);
    d = fmaf(qb.x, k1.x, d);
    d = fmaf(qb.y, k1.y, d);
    d = fmaf(qb.z, k1.z, d);
    d = fmaf(qb.w, k1.w, d);
    d = fmaxf(d * rs, 0.f);
    // one transcendental per step: t = exp(-|d-m|) serves as either the
    // rescale (d>m) or the new term (d<=m); the other factor is exactly 1.
    float t = __expf(-fabsf(d - m));
    bool up = d > m;
    float sc = up ? t : 1.f;
    float e = up ? 1.f : t;
    m = fmaxf(m, d);
    sum = fmaf(sum, sc, e);
    ctx[0] = fmaf(ctx[0], sc, e * v0.x);
    ctx[1] = fmaf(ctx[1], sc, e * v0.y);
    ctx[2] = fmaf(ctx[2], sc, e * v0.z);
    ctx[3] = fmaf(ctx[3], sc, e * v0.w);
    ctx[4] = fmaf(ctx[4], sc, e * v1.x);
    ctx[5] = fmaf(ctx[5], sc, e * v1.y);
    ctx[6] = fmaf(ctx[6], sc, e * v1.z);
    ctx[7] = fmaf(ctx[7], sc, e * v1.w);
  };

#pragma unroll 8
  for (int p = 0; p < 32; ++p) {
    int pi = __shfl(i0, p, 32);
    att_step(tab + (size_t)pi * 24 + 8);
  }
#pragma unroll
  for (int p = 0; p < 13; ++p) {
    int pi = __shfl(i1, p, 32);
    att_step(tab + (size_t)pi * 24 + 8);
  }
  att_step(auxb);        // win  (k at +0, v at +8)
  att_step(auxb + 16);   // rank

  float inv = 1.f / sum;
  float logit = 0.f;
#pragma unroll
  for (int d0 = 0; d0 < 8; ++d0) {
    float c = ctx[d0] * inv;
    c = (c > 0.f) ? c : 0.01f * c;  // leaky_relu
    logit = fmaf(c, sc_w[d0], logit);
  }
  logit += sc_b[0];
  if (lane < PACK_N) out[(size_t)b * PACK_N + lane] = logit;
}

extern "C" void kernel_launch(void* const* d_in, const int* in_sizes, int n_in,
                              void* d_out, int out_size, void* d_ws, size_t ws_size,
                              hipStream_t stream) {
  const int* pool = (const int*)d_in[0];
  const int* pack = (const int*)d_in[1];
  const float* wins = (const float*)d_in[2];
  const float* ranks = (const float*)d_in[3];
  const float* emb = (const float*)d_in[4];
  const float* win_w = (const float*)d_in[5];
  const float* win_b = (const float*)d_in[6];
  const float* rank_w = (const float*)d_in[7];
  const float* rank_b = (const float*)d_in[8];
  const float* q_w = (const float*)d_in[9];
  const float* k_w = (const float*)d_in[10];
  const float* v_w = (const float*)d_in[11];
  const float* sc_w = (const float*)d_in[12];
  const float* sc_b = (const float*)d_in[13];

  float* ws = (float*)d_ws;
  float* wt = ws;
  float* tab = ws + WT_SZ;
  float* aux = ws + WT_SZ + TAB_SZ;
  float* out = (float*)d_out;

  hipLaunchKernelGGL(k_transpose_w, dim3(48), dim3(256), 0, stream,
                     q_w, k_w, v_w, wt);
  hipLaunchKernelGGL(k_build_tab, dim3((V_N + 63) / 64), dim3(256), 0, stream,
                     emb, wt, tab);
  hipLaunchKernelGGL(k_build_aux, dim3(B_N / 16, 2), dim3(256), 0, stream,
                     wins, ranks, win_w, win_b, rank_w, rank_b, wt, aux);
  hipLaunchKernelGGL(k_main, dim3(B_N / 8), dim3(256), 0, stream,
                     pool, pack, tab, aux, sc_w, sc_b, out);
}

// Round 9
// 55.234 us; speedup vs baseline: 1.5012x; 1.1085x over previous
//
#include <hip/hip_runtime.h>

#define B_N 4096
#define POOL_N 45
#define PACK_N 15
#define E_N 512
#define D_N 8
#define V_N 30000

// ws layout (floats):
//   wt  [512][24]  : transposed weights, col j: 0..7=q_w, 8..15=k_w, 16..23=v_w
//   tab [V][24]    : per-card projections, 0..7=q, 8..15=k(relu), 16..23=v(relu)
//   aux [B][32]    : 0..7 k_win, 8..15 v_win, 16..23 k_rank, 24..31 v_rank
#define WT_SZ  (E_N * 24)
#define TAB_SZ (V_N * 24)
#define AUX_SZ (B_N * 32)

// ---------------------------------------------------------------- K0: W^T ---
__global__ __launch_bounds__(256) void k_transpose_w(const float* __restrict__ q_w,
                                                     const float* __restrict__ k_w,
                                                     const float* __restrict__ v_w,
                                                     float* __restrict__ wt) {
  int i = blockIdx.x * 256 + threadIdx.x;  // [0, 512*24)
  if (i >= E_N * 24) return;
  int e = i / 24, j = i % 24;
  float val = (j < 8) ? q_w[j * E_N + e]
            : (j < 16) ? k_w[(j - 8) * E_N + e]
                       : v_w[(j - 16) * E_N + e];
  wt[i] = val;
}

// --------------------------------------------------- K1: projection table ---
// Double-buffered staged GEMM, 64 rows/block, 8 waves, 4 chunks of 128 e.
// Stage: coalesced float4 loads (2 rows x 512B contiguous per wave-instr),
// XOR-swizzled e-major LDS stores (row^= e&63: reads 2-way free, stores
// 4-way). Compute: lane=row, wave-uniform e -> weights via s_load broadcast
// (zero vector-load cost). Loads for chunk k+1 issue before compute of k.
// LDS 2x[128][64] = 64KB -> 2 blocks/CU; grid 469 -> all blocks co-resident.
__global__ __launch_bounds__(512) void k_build_tab(const float* __restrict__ emb,
                                                   const float* __restrict__ wt,
                                                   float* __restrict__ tab) {
  __shared__ float lds[2][128 * 64];  // 64 KB exactly
  int t = threadIdx.x;
  int lane = t & 63;
  int w = __builtin_amdgcn_readfirstlane(t >> 6);  // 0..7, uniform
  int row0 = blockIdx.x * 64;
  int f4 = t & 31;   // e_local quad: e = f4*4 + c
  int r0 = t >> 5;   // 0..15; rows r0 + s*16
  float acc[24];
#pragma unroll
  for (int j = 0; j < 24; ++j) acc[j] = 0.f;

  float4 stg[4];
  // prologue: load + store chunk 0
#pragma unroll
  for (int s = 0; s < 4; ++s) {
    int gr = row0 + r0 + s * 16;
    if (gr >= V_N) gr = V_N - 1;  // clamp (tab store guarded later)
    stg[s] = *(const float4*)(emb + (size_t)gr * E_N + f4 * 4);
  }
#pragma unroll
  for (int s = 0; s < 4; ++s) {
    int row = r0 + s * 16;
    int e0 = f4 * 4;
    lds[0][(e0 + 0) * 64 + (row ^ ((e0 + 0) & 63))] = stg[s].x;
    lds[0][(e0 + 1) * 64 + (row ^ ((e0 + 1) & 63))] = stg[s].y;
    lds[0][(e0 + 2) * 64 + (row ^ ((e0 + 2) & 63))] = stg[s].z;
    lds[0][(e0 + 3) * 64 + (row ^ ((e0 + 3) & 63))] = stg[s].w;
  }

  for (int ch = 0; ch < 4; ++ch) {
    __syncthreads();  // buf[ch&1] ready; buf[(ch+1)&1] free
    if (ch < 3) {
      int eb = (ch + 1) * 128;
#pragma unroll
      for (int s = 0; s < 4; ++s) {
        int gr = row0 + r0 + s * 16;
        if (gr >= V_N) gr = V_N - 1;
        stg[s] = *(const float4*)(emb + (size_t)gr * E_N + eb + f4 * 4);
      }
    }
    // compute chunk ch from lds[ch&1]: wave w covers e_local [w*16, w*16+16)
    {
      const float* wp = wt + (size_t)(ch * 128 + w * 16) * 24;
      const float* buf = lds[ch & 1];
#pragma unroll
      for (int el = 0; el < 16; ++el) {
        int e_loc = w * 16 + el;
        float x = buf[e_loc * 64 + (lane ^ (e_loc & 63))];
        float xr = fmaxf(x, 0.f);
        const float* wr = wp + el * 24;
#pragma unroll
        for (int j = 0; j < 8; ++j) acc[j] = fmaf(x, wr[j], acc[j]);
#pragma unroll
        for (int j = 8; j < 24; ++j) acc[j] = fmaf(xr, wr[j], acc[j]);
      }
    }
    if (ch < 3) {
#pragma unroll
      for (int s = 0; s < 4; ++s) {
        int row = r0 + s * 16;
        int e0 = f4 * 4;
        float* b = (float*)lds[(ch + 1) & 1];
        b[(e0 + 0) * 64 + (row ^ ((e0 + 0) & 63))] = stg[s].x;
        b[(e0 + 1) * 64 + (row ^ ((e0 + 1) & 63))] = stg[s].y;
        b[(e0 + 2) * 64 + (row ^ ((e0 + 2) & 63))] = stg[s].z;
        b[(e0 + 3) * 64 + (row ^ ((e0 + 3) & 63))] = stg[s].w;
      }
    }
  }

  __syncthreads();  // all tile reads done; reuse lds as red[8][64][25]
  float* red = (float*)lds;
#pragma unroll
  for (int j = 0; j < 24; ++j) red[w * 1600 + lane * 25 + j] = acc[j];
  __syncthreads();
  for (int o = t; o < 1536; o += 512) {  // 64 rows x 24 cols
    int row = o / 24, col = o - row * 24;
    int r_out = row0 + row;
    if (r_out < V_N) {
      float v = 0.f;
#pragma unroll
      for (int s = 0; s < 8; ++s) v += red[s * 1600 + row * 25 + col];
      tab[(size_t)r_out * 24 + col] = v;
    }
  }
}

// ------------------------------------------- K2: win/rank k,v rows per b ---
// grid (B/16, 2): 512 blocks. Block 256: thread = (seg 0..15, b-local 0..15);
// each thread covers 32 e-values; LDS reduce over 16 segs.
__global__ __launch_bounds__(256) void k_build_aux(const float* __restrict__ wins,
                                                   const float* __restrict__ ranks,
                                                   const float* __restrict__ win_w,
                                                   const float* __restrict__ win_b,
                                                   const float* __restrict__ rank_w,
                                                   const float* __restrict__ rank_b,
                                                   const float* __restrict__ wt,
                                                   float* __restrict__ aux) {
  __shared__ float red[16][16][17];
  int t = threadIdx.x;
  int bl = t & 15, seg = t >> 4;
  int which = blockIdx.y;
  int b = blockIdx.x * 16 + bl;
  float s = which ? ranks[b] : wins[b];
  const float* ww = which ? rank_w : win_w;
  const float* wb = which ? rank_b : win_b;
  float acc[16];
#pragma unroll
  for (int j = 0; j < 16; ++j) acc[j] = 0.f;
  int e0 = seg * 32;
#pragma unroll 4
  for (int e = e0; e < e0 + 32; ++e) {
    float x = fmaf(s, ww[e], wb[e]);
    float xr = fmaxf(x, 0.f);
    const float* wr = wt + e * 24 + 8;  // k(8) + v(8) columns
#pragma unroll
    for (int j = 0; j < 16; ++j) acc[j] = fmaf(xr, wr[j], acc[j]);
  }
#pragma unroll
  for (int j = 0; j < 16; ++j) red[seg][bl][j] = acc[j];
  __syncthreads();
  int bi = t >> 4, j = t & 15;
  float v = 0.f;
#pragma unroll
  for (int sg = 0; sg < 16; ++sg) v += red[sg][bi][j];
  aux[(size_t)(blockIdx.x * 16 + bi) * 32 + which * 16 + j] = v;
}

// ----------------------------------------------------- K3: attention + out --
// (exact R3 version — known pass) 32-lane group per b; lane = pack slot k.
// Single pass, online softmax; pool indices prefetched + uniform shfl bcast.
__global__ __launch_bounds__(256) void k_main(const int* __restrict__ pool,
                                              const int* __restrict__ pack,
                                              const float* __restrict__ tab,
                                              const float* __restrict__ aux,
                                              const float* __restrict__ sc_w,
                                              const float* __restrict__ sc_b,
                                              float* __restrict__ out) {
  int grp = threadIdx.x >> 5;
  int lane = threadIdx.x & 31;
  int b = blockIdx.x * 8 + grp;
  // prefetch pool indices: lane l holds p=l and p=32+l
  int i0 = pool[(size_t)b * POOL_N + lane];
  int i1 = (lane < POOL_N - 32) ? pool[(size_t)b * POOL_N + 32 + lane] : 0;
  int k = (lane < PACK_N) ? lane : 0;  // clamp idles to avoid OOB gathers
  int qidx = pack[(size_t)b * PACK_N + k];
  const float* qr = tab + (size_t)qidx * 24;
  float4 qa = *(const float4*)qr;
  float4 qb = *(const float4*)(qr + 4);
  const float rs = 0.35355339059327373f;  // 1/sqrt(8)
  const float* auxb = aux + (size_t)b * 32;

  float m = 0.f, sum = 0.f;  // scores relu'd -> max >= 0
  float ctx[8] = {0.f, 0.f, 0.f, 0.f, 0.f, 0.f, 0.f, 0.f};

  auto att_step = [&](const float* kr) {
    float4 k0 = *(const float4*)kr;
    float4 k1 = *(const float4*)(kr + 4);
    float4 v0 = *(const float4*)(kr + 8);
    float4 v1 = *(const float4*)(kr + 12);
    float d = qa.x * k0.x;
    d = fmaf(qa.y, k0.y, d);
    d = fmaf(qa.z, k0.z, d);
    d = fmaf(qa.w, k0.w, d);
    d = fmaf(qb.x, k1.x, d);
    d = fmaf(qb.y, k1.y, d);
    d = fmaf(qb.z, k1.z, d);
    d = fmaf(qb.w, k1.w, d);
    d = fmaxf(d * rs, 0.f);
    // one transcendental per step: t = exp(-|d-m|) serves as either the
    // rescale (d>m) or the new term (d<=m); the other factor is exactly 1.
    float t = __expf(-fabsf(d - m));
    bool up = d > m;
    float sc = up ? t : 1.f;
    float e = up ? 1.f : t;
    m = fmaxf(m, d);
    sum = fmaf(sum, sc, e);
    ctx[0] = fmaf(ctx[0], sc, e * v0.x);
    ctx[1] = fmaf(ctx[1], sc, e * v0.y);
    ctx[2] = fmaf(ctx[2], sc, e * v0.z);
    ctx[3] = fmaf(ctx[3], sc, e * v0.w);
    ctx[4] = fmaf(ctx[4], sc, e * v1.x);
    ctx[5] = fmaf(ctx[5], sc, e * v1.y);
    ctx[6] = fmaf(ctx[6], sc, e * v1.z);
    ctx[7] = fmaf(ctx[7], sc, e * v1.w);
  };

#pragma unroll 8
  for (int p = 0; p < 32; ++p) {
    int pi = __shfl(i0, p, 32);
    att_step(tab + (size_t)pi * 24 + 8);
  }
#pragma unroll
  for (int p = 0; p < 13; ++p) {
    int pi = __shfl(i1, p, 32);
    att_step(tab + (size_t)pi * 24 + 8);
  }
  att_step(auxb);        // win  (k at +0, v at +8)
  att_step(auxb + 16);   // rank

  float inv = 1.f / sum;
  float logit = 0.f;
#pragma unroll
  for (int d0 = 0; d0 < 8; ++d0) {
    float c = ctx[d0] * inv;
    c = (c > 0.f) ? c : 0.01f * c;  // leaky_relu
    logit = fmaf(c, sc_w[d0], logit);
  }
  logit += sc_b[0];
  if (lane < PACK_N) out[(size_t)b * PACK_N + lane] = logit;
}

extern "C" void kernel_launch(void* const* d_in, const int* in_sizes, int n_in,
                              void* d_out, int out_size, void* d_ws, size_t ws_size,
                              hipStream_t stream) {
  const int* pool = (const int*)d_in[0];
  const int* pack = (const int*)d_in[1];
  const float* wins = (const float*)d_in[2];
  const float* ranks = (const float*)d_in[3];
  const float* emb = (const float*)d_in[4];
  const float* win_w = (const float*)d_in[5];
  const float* win_b = (const float*)d_in[6];
  const float* rank_w = (const float*)d_in[7];
  const float* rank_b = (const float*)d_in[8];
  const float* q_w = (const float*)d_in[9];
  const float* k_w = (const float*)d_in[10];
  const float* v_w = (const float*)d_in[11];
  const float* sc_w = (const float*)d_in[12];
  const float* sc_b = (const float*)d_in[13];

  float* ws = (float*)d_ws;
  float* wt = ws;
  float* tab = ws + WT_SZ;
  float* aux = ws + WT_SZ + TAB_SZ;
  float* out = (float*)d_out;

  hipLaunchKernelGGL(k_transpose_w, dim3(48), dim3(256), 0, stream,
                     q_w, k_w, v_w, wt);
  hipLaunchKernelGGL(k_build_tab, dim3((V_N + 63) / 64), dim3(512), 0, stream,
                     emb, wt, tab);
  hipLaunchKernelGGL(k_build_aux, dim3(B_N / 16, 2), dim3(256), 0, stream,
                     wins, ranks, win_w, win_b, rank_w, rank_b, wt, aux);
  hipLaunchKernelGGL(k_main, dim3(B_N / 8), dim3(256), 0, stream,
                     pool, pack, tab, aux, sc_w, sc_b, out);
}